// Round 14
// baseline (196.123 us; speedup 1.0000x reference)
//
#include <hip/hip_runtime.h>

#define KD 1024   // D
#define KI 2048   // I
#define KB 2      // B
#define KS 1024   // S
#define KC 64     // C
#define KN 16     // N chunks
#define KEPS 1e-6f

typedef __bf16 bf16x8 __attribute__((ext_vector_type(8)));
typedef __bf16 bf16x4 __attribute__((ext_vector_type(4)));
typedef float f32x4 __attribute__((ext_vector_type(4)));

__device__ __forceinline__ float sigf(float x){ return 1.0f/(1.0f+__expf(-x)); }
__device__ __forceinline__ float siluf(float x){ return x*sigf(x); }
__device__ __forceinline__ float dsiluf(float x){ float s=sigf(x); return s*(1.0f+x*(1.0f-s)); }

// width-16 global->LDS DMA; LDS dest is wave-uniform base + lane*16
__device__ __forceinline__ void gld16(const __bf16* g, __bf16* l) {
  __builtin_amdgcn_global_load_lds(
    (const __attribute__((address_space(1))) unsigned int*)g,
    (__attribute__((address_space(3))) unsigned int*)l, 16, 0, 0);
}

#define WAIT_VM6()  asm volatile("s_waitcnt vmcnt(6)" ::: "memory")
#define WAIT_VM4()  asm volatile("s_waitcnt vmcnt(4)" ::: "memory")
#define WAIT_VM0()  asm volatile("s_waitcnt vmcnt(0)" ::: "memory")
#define WAIT_LGKM() asm volatile("s_waitcnt lgkmcnt(0)" ::: "memory")
#define BAR()       __builtin_amdgcn_s_barrier()

// ---------------- transpose body, caller LDS (needs >= 64*65 floats) -------
__device__ __forceinline__ void tconv_bodyP(float* T, const __bf16* in, __bf16* out,
                                            int R, int Cc, int bx, int by)
{
  const int r0 = by*64, c0 = bx*64;
  const int tx = threadIdx.x & 15, ty = threadIdx.x >> 4;
  #pragma unroll
  for (int i=0;i<4;i++){
    const int r = r0 + ty + i*16;
    const bf16x4 v = *(const bf16x4*)(in + (size_t)r*Cc + c0 + tx*4);
    T[(ty+i*16)*65 + tx*4+0]=(float)v[0]; T[(ty+i*16)*65 + tx*4+1]=(float)v[1];
    T[(ty+i*16)*65 + tx*4+2]=(float)v[2]; T[(ty+i*16)*65 + tx*4+3]=(float)v[3];
  }
  __syncthreads();
  #pragma unroll
  for (int i=0;i<4;i++){
    bf16x4 o = { (__bf16)T[(tx*4+0)*65 + ty+i*16], (__bf16)T[(tx*4+1)*65 + ty+i*16],
                 (__bf16)T[(tx*4+2)*65 + ty+i*16], (__bf16)T[(tx*4+3)*65 + ty+i*16] };
    *(bf16x4*)(out + (size_t)(c0+ty+i*16)*R + r0 + tx*4) = o;
  }
}

// fp32-source transpose with own LDS (prep only)
__device__ __forceinline__ void tconv_bodyF(const float* in, __bf16* out,
                                            int R, int Cc, int bx, int by)
{
  __shared__ float T[64][65];
  const int r0 = by*64, c0 = bx*64;
  const int tx = threadIdx.x & 15, ty = threadIdx.x >> 4;
  #pragma unroll
  for (int i=0;i<4;i++){
    const int r = r0 + ty + i*16;
    const float4 v = *(const float4*)(in + (size_t)r*Cc + c0 + tx*4);
    T[ty+i*16][tx*4+0]=v.x; T[ty+i*16][tx*4+1]=v.y;
    T[ty+i*16][tx*4+2]=v.z; T[ty+i*16][tx*4+3]=v.w;
  }
  __syncthreads();
  #pragma unroll
  for (int i=0;i<4;i++){
    bf16x4 o = { (__bf16)T[tx*4+0][ty+i*16], (__bf16)T[tx*4+1][ty+i*16],
                 (__bf16)T[tx*4+2][ty+i*16], (__bf16)T[tx*4+3][ty+i*16] };
    *(bf16x4*)(out + (size_t)(c0+ty+i*16)*R + r0 + tx*4) = o;
  }
}

// ---------------- prep: convert (x-blocks also gate partials) + w2^T + gl=0
__global__ __launch_bounds__(256) void prep_kernel(
  const float* __restrict__ x, const float* __restrict__ wk, const float* __restrict__ wv,
  const float* __restrict__ wq, const float* __restrict__ w1, const float* __restrict__ w2,
  const float* __restrict__ aw, const float* __restrict__ tw, const float* __restrict__ ew,
  __bf16* __restrict__ xb, __bf16* __restrict__ wkb, __bf16* __restrict__ wvb,
  __bf16* __restrict__ wqb, __bf16* __restrict__ w1b, __bf16* __restrict__ w2b,
  __bf16* __restrict__ w2tb, float* __restrict__ part, float* __restrict__ gl)
{
  const int g = blockIdx.x;
  if (g < 2048) {
    const int i = g*256 + threadIdx.x;          // float4 index into x
    const float4 xv = *(const float4*)(x + (size_t)i*4);
    bf16x4 o = { (__bf16)xv.x, (__bf16)xv.y, (__bf16)xv.z, (__bf16)xv.w };
    *(bf16x4*)(xb + (size_t)i*4) = o;
    const size_t co = (size_t)(i & 16383) * 4;  // chunk-local element offset
    const float4 av = *(const float4*)(aw + co);
    const float4 tv = *(const float4*)(tw + co);
    const float4 ev = *(const float4*)(ew + co);
    float da = xv.x*av.x + xv.y*av.y + xv.z*av.z + xv.w*av.w;
    float dt = xv.x*tv.x + xv.y*tv.y + xv.z*tv.z + xv.w*tv.w;
    float de = xv.x*ev.x + xv.y*ev.y + xv.z*ev.z + xv.w*ev.w;
    __shared__ float sA[256], sT[256], sE[256];
    sA[threadIdx.x]=da; sT[threadIdx.x]=dt; sE[threadIdx.x]=de;
    __syncthreads();
    for (int s=128;s>0;s>>=1){
      if ((int)threadIdx.x < s){
        sA[threadIdx.x]+=sA[threadIdx.x+s];
        sT[threadIdx.x]+=sT[threadIdx.x+s];
        sE[threadIdx.x]+=sE[threadIdx.x+s];
      }
      __syncthreads();
    }
    if (threadIdx.x==0){
      part[g] = sA[0]; part[2048+g] = sT[0]; part[4096+g] = sE[0];
    }
  } else if (g < 9216) {
    const long t = (long)g*256 + threadIdx.x;   // float4 index
    const float* s; __bf16* d; long i;
    if (t < 786432)       { s=wk; d=wkb; i=t-524288; }
    else if (t < 1048576) { s=wv; d=wvb; i=t-786432; }
    else if (t < 1310720) { s=wq; d=wqb; i=t-1048576; }
    else if (t < 1835008) { s=w1; d=w1b; i=t-1310720; }
    else                  { s=w2; d=w2b; i=t-1835008; }
    const float4 v = *(const float4*)(s + i*4);
    bf16x4 o = { (__bf16)v.x, (__bf16)v.y, (__bf16)v.z, (__bf16)v.w };
    *(bf16x4*)(d + i*4) = o;
  } else if (g < 9728) {
    const int gg = g - 9216;
    tconv_bodyF(w2, w2tb, 1024, 2048, gg & 31, gg >> 5);
  } else {
    const int gg = g - 9728;                    // 32 blocks zero gl
    float4 z = {0.f,0.f,0.f,0.f};
    *(float4*)(gl + (size_t)gg*1024 + threadIdx.x*4) = z;
  }
}

// ---------------- MFMA bf16 GEMM body, counted-vmcnt: C = A*B^T ------------
// BM=128, BN=64, BK=64, K=1024 (16 steps). 4 waves, wave tile 64x32.
// Prefetch loads for t+1 stay IN FLIGHT across the barriers (vmcnt(6), not 0).
// MODE: 0 plain, 1 proj mux (z selects B), 2 k-split (z = K half)
// EPI: 0 F0=acc; 2 Oa=silu & Ob=dsilu (+WT: OT=silu^T);
//      3 (WT) OT=(acc*Aux)^T only; 4 Oa=silu; 6 Oa[z*M*N]=bf16(acc);
//      5 proj mux all-bf16: bz0->Oa, bz1->Ob, bz2->OT (silu)
template<int EPI, int MODE, int WT>
__device__ __forceinline__ void mgemm_body(
    __bf16* As, __bf16* Bs,
    const __bf16* __restrict__ A, const __bf16* __restrict__ B0,
    const __bf16* __restrict__ B1, const __bf16* __restrict__ B2,
    float* __restrict__ F0, float* __restrict__ F1,
    __bf16* __restrict__ Oa, __bf16* __restrict__ Ob, const __bf16* __restrict__ Aux,
    __bf16* __restrict__ OT, int ldt,
    int M, int Nn, int lda, int ldb, long bstr,
    int bx, int by, int bz)
{
  const int n0 = bx * 64;
  const int m0 = by * 128;
  const __bf16* Bp = B0;
  if (MODE==1) { if (bz==1) Bp=B1; else if (bz==2) Bp=B2; }
  float* F0p = F0;
  int koff0 = 0;
  if (MODE==2) { koff0 = bz << 10; }
  Bp += (size_t)(m0 >> 10) * (size_t)bstr;
  const int tid = threadIdx.x, wv = tid >> 6, lane = tid & 63;
  const int wm = (wv >> 1) << 6, wn = (wv & 1) << 5;
  const int fr = lane & 15, fg = lane >> 4;
  const int lr = lane >> 3, lc = lane & 7;
  const __bf16* asrc[4]; __bf16* adst[4];
  const __bf16* bsrc[2]; __bf16* bdst[2];
  #pragma unroll
  for (int i=0;i<4;i++){
    const int rowbase=(wv*4+i)*8, row=rowbase+lr;
    asrc[i] = A + (size_t)(m0+row)*lda + koff0 + ((lc^(row&7))<<3);
    adst[i] = As + rowbase*64;
  }
  #pragma unroll
  for (int i=0;i<2;i++){
    const int rowbase=(wv*2+i)*8, row=rowbase+lr;
    bsrc[i] = Bp + (size_t)(n0+row)*ldb + koff0 + ((lc^(row&7))<<3);
    bdst[i] = Bs + rowbase*64;
  }
  f32x4 acc[4][2] = {};
  #pragma unroll
  for (int i=0;i<4;i++) gld16(asrc[i], adst[i]);
  #pragma unroll
  for (int i=0;i<2;i++) gld16(bsrc[i], bdst[i]);
  WAIT_VM0();
  BAR();
  #pragma unroll 2
  for (int t=0;t<16;++t){
    const int p = t & 1;
    if (t < 15){
      const int ko = (t+1) << 6;
      const int q = p ^ 1;
      #pragma unroll
      for (int i=0;i<4;i++) gld16(asrc[i]+ko, adst[i]+q*8192);
      #pragma unroll
      for (int i=0;i<2;i++) gld16(bsrc[i]+ko, bdst[i]+q*4096);
      WAIT_VM6();            // loads(t) done; loads(t+1) stay in flight
    } else {
      WAIT_VM0();
    }
    BAR();
    #pragma unroll
    for (int ks=0;ks<2;++ks){
      bf16x8 af[4], bfv[2];
      #pragma unroll
      for (int mi=0;mi<4;++mi){
        const int r = wm + mi*16 + fr;
        af[mi] = *(const bf16x8*)(As + p*8192 + r*64 + ((((ks<<2)+fg)^(r&7))<<3));
      }
      #pragma unroll
      for (int ni=0;ni<2;++ni){
        const int r = wn + ni*16 + fr;
        bfv[ni] = *(const bf16x8*)(Bs + p*4096 + r*64 + ((((ks<<2)+fg)^(r&7))<<3));
      }
      #pragma unroll
      for (int mi=0;mi<4;++mi)
        #pragma unroll
        for (int ni=0;ni<2;++ni)
          acc[mi][ni] = __builtin_amdgcn_mfma_f32_16x16x32_bf16(af[mi], bfv[ni], acc[mi][ni], 0,0,0);
    }
    WAIT_LGKM();             // all LDS reads landed in regs before buffer reuse
    BAR();
  }
  __bf16* T = As;   // reuse staging LDS for transpose epilogue
  #pragma unroll
  for (int mi=0;mi<4;++mi){
    #pragma unroll
    for (int ni=0;ni<2;++ni){
      bf16x4 tv;
      #pragma unroll
      for (int j=0;j<4;++j){
        const int m = m0 + wm + mi*16 + fg*4 + j;
        const int n = n0 + wn + ni*16 + fr;
        const size_t idx = (size_t)m * Nn + n;
        const float v = acc[mi][ni][j];
        float tval = 0.f;
        if (EPI==0) F0p[idx] = v;
        else if (EPI==2) { const float sv = siluf(v); Oa[idx]=(__bf16)sv; Ob[idx]=(__bf16)dsiluf(v); tval=sv; }
        else if (EPI==3) tval = v * (float)Aux[idx];
        else if (EPI==4) Oa[idx] = (__bf16)siluf(v);
        else if (EPI==5) {
          const __bf16 sv = (__bf16)siluf(v);
          if (bz==0) Oa[idx] = sv;
          else if (bz==1) Ob[idx] = sv;
          else OT[idx] = sv;
        }
        else if (EPI==6) Oa[(size_t)bz*M*Nn + idx] = (__bf16)v;
        if (WT) tv[j] = (__bf16)tval;
      }
      if (WT){
        const int nl = wn + ni*16 + fr;
        const int ml = wm + mi*16 + fg*4;
        *(bf16x4*)(T + nl*128 + (ml ^ ((nl&7)<<3))) = tv;
      }
    }
  }
  if (WT){
    __syncthreads();
    const int tn = tid >> 2, tc = tid & 3;
    #pragma unroll
    for (int u=0;u<4;++u){
      const int m8 = tc*32 + u*8;
      const bf16x8 v = *(const bf16x8*)(T + tn*128 + (m8 ^ ((tn&7)<<3)));
      *(bf16x8*)(OT + (size_t)(n0+tn)*ldt + m0 + m8) = v;
    }
  }
}

template<int EPI, int MODE, int WT>
__global__ __launch_bounds__(256) void mgemm2(
    const __bf16* __restrict__ A, const __bf16* __restrict__ B0,
    const __bf16* __restrict__ B1, const __bf16* __restrict__ B2,
    float* __restrict__ F0, float* __restrict__ F1,
    __bf16* __restrict__ Oa, __bf16* __restrict__ Ob, const __bf16* __restrict__ Aux,
    __bf16* __restrict__ OT, int ldt,
    int M, int Nn, int lda, int ldb, long bstr)
{
  __shared__ __bf16 As[2*128*64];
  __shared__ __bf16 Bs[2*64*64];
  mgemm_body<EPI,MODE,WT>(As, Bs, A, B0, B1, B2, F0, F1, Oa, Ob, Aux, OT, ldt,
                          M, Nn, lda, ldb, bstr, blockIdx.x, blockIdx.y, blockIdx.z);
}

// ---------------- a-GEMM (h,dsilu,hT) + kT transpose in one launch ---------
__global__ __launch_bounds__(256) void gemm_a_kernel(
    const __bf16* __restrict__ kb16, const __bf16* __restrict__ w1b,
    __bf16* __restrict__ hb16, __bf16* __restrict__ db16, __bf16* __restrict__ hT,
    __bf16* __restrict__ kT)
{
  __shared__ __bf16 As[2*128*64];
  __shared__ __bf16 Bs[2*64*64];
  const int g = blockIdx.x;
  if (g < 512)
    mgemm_body<2,0,1>(As, Bs, kb16, w1b, nullptr, nullptr, nullptr, nullptr,
                      hb16, db16, nullptr, hT, 2048, 2048, 2048, 1024, 1024, 0,
                      g & 31, g >> 5, 0);
  else {
    const int t = g - 512;
    tconv_bodyP((float*)As, kb16, kT, 2048, 1024, t & 15, t >> 4);
  }
}

// ---------------- ga-GEMM (gaT only) + gyT transpose in one launch ---------
__global__ __launch_bounds__(256) void gemm_ga_kernel(
    const __bf16* __restrict__ gyb, const __bf16* __restrict__ w2tb,
    const __bf16* __restrict__ db16, __bf16* __restrict__ gaT,
    __bf16* __restrict__ gyT)
{
  __shared__ __bf16 As[2*128*64];
  __shared__ __bf16 Bs[2*64*64];
  const int g = blockIdx.x;
  if (g < 512)
    mgemm_body<3,0,1>(As, Bs, gyb, w2tb, nullptr, nullptr, nullptr, nullptr,
                      nullptr, nullptr, db16, gaT, 2048, 2048, 2048, 1024, 1024, 0,
                      g & 31, g >> 5, 0);
  else {
    const int t = g - 512;
    tconv_bodyP((float*)As, gyb, gyT, 2048, 1024, t & 15, t >> 4);
  }
}

// ---------------- dual scan-weighted GEMM body, 64x64 tile -----------------
// Smaller tile -> 32 KB LDS, less VGPR -> 4-5 blocks/CU (2x occupancy) for
// this latency-bound kernel. 4 waves, wave tile 32x32, vmcnt(4) pipeline.
__device__ __forceinline__ void wacc_body(
    __bf16* As, __bf16* Bs,   // each 2*64*64
    const __bf16* __restrict__ A, const __bf16* __restrict__ B,
    const __bf16* __restrict__ Winit,
    const float* __restrict__ cm, const float* __restrict__ cs,
    const float* __restrict__ Pw,
    float* __restrict__ outM, __bf16* __restrict__ outMb, float* __restrict__ outS,
    int M, int Nn, int lda, int ldb, int n0, int m0, int bz)
{
  const int koff0 = bz << 10;
  const int tid = threadIdx.x, wv = tid >> 6, lane = tid & 63;
  const int wm = (wv >> 1) << 5, wn = (wv & 1) << 5;
  const int fr = lane & 15, fg = lane >> 4;
  const int lr = lane >> 3, lc = lane & 7;
  float cmr[KN], csr[KN];
  #pragma unroll
  for (int n=0;n<KN;n++){ cmr[n]=cm[bz*KN+n]; csr[n]=cs[bz*KN+n]; }
  const __bf16* asrc[2]; __bf16* adst[2];
  const __bf16* bsrc[2]; __bf16* bdst[2];
  #pragma unroll
  for (int i=0;i<2;i++){
    const int rowbase=(wv*2+i)*8, row=rowbase+lr;
    asrc[i] = A + (size_t)(m0+row)*lda + koff0 + ((lc^(row&7))<<3);
    adst[i] = As + rowbase*64;
    bsrc[i] = B + (size_t)(n0+row)*ldb + koff0 + ((lc^(row&7))<<3);
    bdst[i] = Bs + rowbase*64;
  }
  f32x4 accM[2][2] = {}, accS[2][2] = {};
  asm volatile("s_waitcnt vmcnt(0) lgkmcnt(0)" ::: "memory");  // fence preloads
  #pragma unroll
  for (int i=0;i<2;i++) gld16(asrc[i], adst[i]);
  #pragma unroll
  for (int i=0;i<2;i++) gld16(bsrc[i], bdst[i]);
  WAIT_VM0();
  BAR();
  #pragma unroll 2
  for (int t=0;t<16;++t){
    const int p = t & 1;
    const float cmc = cmr[t], csc = csr[t];
    if (t < 15){
      const int ko = (t+1) << 6;
      const int q = p ^ 1;
      #pragma unroll
      for (int i=0;i<2;i++) gld16(asrc[i]+ko, adst[i]+q*4096);
      #pragma unroll
      for (int i=0;i<2;i++) gld16(bsrc[i]+ko, bdst[i]+q*4096);
      WAIT_VM4();
    } else {
      WAIT_VM0();
    }
    BAR();
    bf16x8 a0[2], a1[2], b0[2], b1[2];
    #pragma unroll
    for (int mi=0;mi<2;++mi){
      const int r = wm + mi*16 + fr;
      a0[mi] = *(const bf16x8*)(As + p*4096 + r*64 + (((0+fg)^(r&7))<<3));
      a1[mi] = *(const bf16x8*)(As + p*4096 + r*64 + (((4+fg)^(r&7))<<3));
    }
    #pragma unroll
    for (int ni=0;ni<2;++ni){
      const int r = wn + ni*16 + fr;
      b0[ni] = *(const bf16x8*)(Bs + p*4096 + r*64 + (((0+fg)^(r&7))<<3));
      b1[ni] = *(const bf16x8*)(Bs + p*4096 + r*64 + (((4+fg)^(r&7))<<3));
    }
    #pragma unroll
    for (int mi=0;mi<2;++mi){
      #pragma unroll
      for (int ni=0;ni<2;++ni){
        const f32x4 zf = {0.f,0.f,0.f,0.f};
        f32x4 P = __builtin_amdgcn_mfma_f32_16x16x32_bf16(a0[mi], b0[ni], zf, 0,0,0);
        P = __builtin_amdgcn_mfma_f32_16x16x32_bf16(a1[mi], b1[ni], P, 0,0,0);
        accM[mi][ni] += P * cmc;
        accS[mi][ni] += P * csc;
      }
    }
    WAIT_LGKM();
    BAR();
  }
  const float pw = Pw[bz];
  float* Tf = (float*)As;   // 16 KB = 64x64 fp32 tile (fits As exactly)
  const int orow = tid >> 4, oc4 = (tid & 15) << 2;
  // ---- M output: stage, then coalesced 256B-row writes (+bf16 copy) ----
  #pragma unroll
  for (int mi=0;mi<2;++mi){
    #pragma unroll
    for (int ni=0;ni<2;++ni){
      #pragma unroll
      for (int j=0;j<4;++j){
        const int ml = wm + mi*16 + fg*4 + j;
        const int nl = wn + ni*16 + fr;
        const size_t widx = (size_t)(m0+ml)*Nn + (n0+nl);
        Tf[ml*64 + nl] = pw * (float)Winit[widx] + accM[mi][ni][j];
      }
    }
  }
  __syncthreads();
  #pragma unroll
  for (int ps=0; ps<4; ++ps){
    const int r = orow + ps*16;
    const float4 v = *(const float4*)&Tf[r*64 + oc4];
    const size_t oidx = (size_t)bz*M*Nn + (size_t)(m0+r)*Nn + n0 + oc4;
    *(float4*)&outM[oidx] = v;
    bf16x4 vb = { (__bf16)v.x, (__bf16)v.y, (__bf16)v.z, (__bf16)v.w };
    *(bf16x4*)&outMb[oidx] = vb;
  }
  __syncthreads();
  // ---- S output ----
  #pragma unroll
  for (int mi=0;mi<2;++mi){
    #pragma unroll
    for (int ni=0;ni<2;++ni){
      #pragma unroll
      for (int j=0;j<4;++j){
        const int ml = wm + mi*16 + fg*4 + j;
        const int nl = wn + ni*16 + fr;
        Tf[ml*64 + nl] = accS[mi][ni][j];
      }
    }
  }
  __syncthreads();
  #pragma unroll
  for (int ps=0; ps<4; ++ps){
    const int r = orow + ps*16;
    const float4 v = *(const float4*)&Tf[r*64 + oc4];
    const size_t oidx = (size_t)bz*M*Nn + (size_t)(m0+r)*Nn + n0 + oc4;
    *(float4*)&outS[oidx] = v;
  }
}

// ---------------- merged wacc1 + wacc2 + glcomb (64x64 tiles) --------------
// Section-local XCD swizzle on 1024-block sections (round-13: -33% FETCH).
__global__ __launch_bounds__(256) void waccall_kernel(
    const __bf16* __restrict__ gaT, const __bf16* __restrict__ kT, const __bf16* __restrict__ w1b,
    const __bf16* __restrict__ gyT, const __bf16* __restrict__ hT, const __bf16* __restrict__ w2b,
    const float* __restrict__ gl, const float* __restrict__ lnw,
    const float* __restrict__ cm, const float* __restrict__ cs, const float* __restrict__ Pw,
    float* __restrict__ nw1, __bf16* __restrict__ nw1b, float* __restrict__ ns1,
    float* __restrict__ nw2, __bf16* __restrict__ nw2b, float* __restrict__ ns2,
    float* __restrict__ nln, float* __restrict__ nsl)
{
  __shared__ __bf16 As[2*64*64];
  __shared__ __bf16 Bs[2*64*64];
  int g = blockIdx.x;
  if (g < 1024) g = ((g & 7) << 7) | (g >> 3);                          // bijective [0,1024)
  else if (g < 2048) { int t = g - 1024; g = 1024 + (((t & 7) << 7) | (t >> 3)); }
  if (g < 1024){
    const int bz = g >> 9, rem = g & 511;      // 16 n-tiles x 32 m-tiles
    wacc_body(As, Bs, gaT, kT, w1b, cm, cs, Pw, nw1, nw1b, ns1,
              2048, 1024, 2048, 2048, (rem & 15)*64, (rem >> 4)*64, bz);
  } else if (g < 2048){
    const int t = g - 1024;
    const int bz = t >> 9, rem = t & 511;      // 32 n-tiles x 16 m-tiles
    wacc_body(As, Bs, gyT, hT, w2b, cm, cs, Pw, nw2, nw2b, ns2,
              1024, 2048, 2048, 2048, (rem & 31)*64, (rem >> 5)*64, bz);
  } else {
    const int idx = (g - 2048)*256 + threadIdx.x;
    const int b = idx >> 10, d = idx & (KD-1);
    float am=0.f, as=0.f;
    for (int n=0;n<KN;n++){
      const float gv = gl[(size_t)(b*KN+n)*KD + d];
      am += cm[b*KN+n]*gv; as += cs[b*KN+n]*gv;
    }
    nln[idx] = Pw[b]*lnw[d] + am;
    nsl[idx] = as;
  }
}

// ---------------- rmsnorm for k,q from bf16 (+ scan coef at y==2) ----------
__global__ __launch_bounds__(256) void rmsfuse_kernel(
    const __bf16* __restrict__ kv, const float* __restrict__ kw, __bf16* __restrict__ k16,
    const __bf16* __restrict__ qv, const float* __restrict__ qw, __bf16* __restrict__ q16,
    const float* __restrict__ part, float* __restrict__ cm, float* __restrict__ cs,
    float* __restrict__ Pw, float* __restrict__ theta)
{
  if (blockIdx.y == 2){
    if (blockIdx.x != 0) return;
    __shared__ float P[32][8][3];
    const int bn = threadIdx.x >> 3, sg = threadIdx.x & 7;
    float s0=0.f, s1=0.f, s2=0.f;
    #pragma unroll
    for (int u=0;u<8;u++){
      const int seg = bn*64 + sg*8 + u;
      s0 += part[seg]; s1 += part[2048+seg]; s2 += part[4096+seg];
    }
    P[bn][sg][0]=s0; P[bn][sg][1]=s1; P[bn][sg][2]=s2;
    __syncthreads();
    if ((int)threadIdx.x < KB){
      const int b = threadIdx.x;
      float al[KN], et[KN];
      for (int n=0;n<KN;n++){
        const int c = b*KN+n;
        float sa=0.f, st=0.f, se=0.f;
        #pragma unroll
        for (int k=0;k<8;k++){ sa+=P[c][k][0]; st+=P[c][k][1]; se+=P[c][k][2]; }
        al[n]=sigf(sa); theta[c]=sigf(st)*0.01f; et[n]=sigf(se);
      }
      float prodE = 1.f;
      for (int j=KN-1;j>=0;j--){ cs[b*KN+j] = -prodE; prodE *= et[j]; }
      float Ac[KN]; Ac[KN-1]=1.f;
      for (int t=KN-2;t>=0;t--) Ac[t] = Ac[t+1]*(1.f-al[t+1]);
      for (int j=0;j<KN;j++){
        float inner=0.f, E=1.f;
        for (int t=j;t<KN;t++){ inner += Ac[t]*E; if (t+1<KN) E *= et[t+1]; }
        cm[b*KN+j] = -inner;
      }
      float pw=1.f;
      for (int n=0;n<KN;n++) pw *= (1.f-al[n]);
      Pw[b]=pw;
    }
    return;
  }
  const __bf16* v; const float* w; __bf16* o16;
  if (blockIdx.y == 0){ v=kv; w=kw; o16=k16; } else { v=qv; w=qw; o16=q16; }
  const int row = blockIdx.x * 4 + (threadIdx.x >> 6);
  const int lane = threadIdx.x & 63;
  const __bf16* pr = v + (size_t)row * KD + lane*16;   // 16 contiguous per lane
  const bf16x8 a0 = *(const bf16x8*)pr;
  const bf16x8 a1 = *(const bf16x8*)(pr + 8);
  float vals[16]; float ss = 0.f;
  #pragma unroll
  for (int j=0;j<8;j++){ vals[j]=(float)a0[j]; vals[8+j]=(float)a1[j]; }
  #pragma unroll
  for (int j=0;j<16;j++) ss += vals[j]*vals[j];
  #pragma unroll
  for (int o=32;o>0;o>>=1) ss += __shfl_xor(ss, o, 64);
  const float inv = rsqrtf(ss * (1.0f/KD) + KEPS);
  const float* wp = w + lane*16;
  const float4 w0 = *(const float4*)(wp),   w1 = *(const float4*)(wp+4);
  const float4 w2 = *(const float4*)(wp+8), w3 = *(const float4*)(wp+12);
  const float wa[16] = { w0.x,w0.y,w0.z,w0.w, w1.x,w1.y,w1.z,w1.w,
                         w2.x,w2.y,w2.z,w2.w, w3.x,w3.y,w3.z,w3.w };
  bf16x8 o0, o1;
  #pragma unroll
  for (int j=0;j<8;j++){
    o0[j] = (__bf16)(vals[j]*inv*wa[j]);
    o1[j] = (__bf16)(vals[8+j]*inv*wa[8+j]);
  }
  __bf16* op = o16 + (size_t)row * KD + lane*16;
  *(bf16x8*)op = o0;
  *(bf16x8*)(op + 8) = o1;
}

// ---------------- per-row backward (y = bf16 halves), gl via atomics -------
__global__ __launch_bounds__(256) void rms_grad_kernel(
    const __bf16* __restrict__ y16,
    const __bf16* __restrict__ k16, const __bf16* __restrict__ v16,
    const float* __restrict__ lnw, const float* __restrict__ theta,
    __bf16* __restrict__ gy, float* __restrict__ gl)
{
  const int wv = threadIdx.x >> 6;
  const int row = blockIdx.x * 4 + wv;
  const int lane = threadIdx.x & 63;
  const int chunk = blockIdx.x >> 4;
  const float th2 = theta[chunk] * (2.0f / KD);
  const __bf16* yr0 = y16 + (size_t)row * KD;
  const __bf16* yr1 = y16 + 2097152 + (size_t)row * KD;
  const __bf16* kr = k16 + (size_t)row * KD;
  const __bf16* vr = v16 + (size_t)row * KD;
  float yv[16]; float ss = 0.f;
  #pragma unroll
  for (int l=0;l<16;l++){
    const int d = lane + (l<<6);
    yv[l] = (float)yr0[d] + (float)yr1[d]; ss += yv[l]*yv[l];
  }
  #pragma unroll
  for (int o=32;o>0;o>>=1) ss += __shfl_xor(ss, o, 64);
  const float inv = rsqrtf(ss * (1.0f/KD) + KEPS);
  float gzv[16]; float sdot = 0.f;
  #pragma unroll
  for (int l=0;l<16;l++){
    const int d = lane + (l<<6);
    const float gz = th2 * ((float)kr[d] + yv[l]*inv*lnw[d] - (float)vr[d]);
    gzv[l] = gz;
    sdot += gz * lnw[d] * yv[l];
  }
  #pragma unroll
  for (int o=32;o>0;o>>=1) sdot += __shfl_xor(sdot, o, 64);
  const float c3 = inv*inv*inv * (1.0f/KD) * sdot;
  __bf16* gyr = gy + (size_t)row * KD;
  __shared__ float L[4][KD];
  #pragma unroll
  for (int l=0;l<16;l++){
    const int d = lane + (l<<6);
    gyr[d] = (__bf16)(inv * lnw[d] * gzv[l] - c3 * yv[l]);
    L[wv][d] = gzv[l] * yv[l] * inv;
  }
  __syncthreads();
  if (wv == 0){
    float* glc = gl + (size_t)chunk * KD;
    #pragma unroll
    for (int l=0;l<16;l++){
      const int d = lane + (l<<6);
      atomicAdd(&glc[d], L[0][d]+L[1][d]+L[2][d]+L[3][d]);
    }
  }
}

// ---------------- final out (yq = bf16 halves, q from bf16) ----------------
__global__ __launch_bounds__(256) void final_out_kernel(
    const __bf16* __restrict__ q16, const __bf16* __restrict__ yq16,
    const float* __restrict__ nln, float* __restrict__ out)
{
  const int row = blockIdx.x * 4 + (threadIdx.x >> 6);
  const int lane = threadIdx.x & 63;
  const int b = row >> 10;
  float yv[16]; float ss = 0.f;
  #pragma unroll
  for (int l=0;l<16;l++){
    const int d = lane + (l<<6);
    yv[l] = (float)yq16[(size_t)row*KD + d] + (float)yq16[2097152 + (size_t)row*KD + d];
    ss += yv[l]*yv[l];
  }
  #pragma unroll
  for (int o=32;o>0;o>>=1) ss += __shfl_xor(ss, o, 64);
  const float inv = rsqrtf(ss * (1.0f/KD) + KEPS);
  #pragma unroll
  for (int l=0;l<16;l++){
    const int d = lane + (l<<6);
    out[(size_t)row*KD + d] = (float)q16[(size_t)row*KD + d] + yv[l]*inv*nln[b*KD + d];
  }
}

extern "C" void kernel_launch(void* const* d_in, const int* in_sizes, int n_in,
                              void* d_out, int out_size, void* d_ws, size_t ws_size,
                              hipStream_t stream)
{
  const float* x    = (const float*)d_in[0];
  const float* w1   = (const float*)d_in[1];
  const float* w2   = (const float*)d_in[2];
  const float* lnw  = (const float*)d_in[3];
  const float* wq   = (const float*)d_in[4];
  const float* wk   = (const float*)d_in[5];
  const float* wv   = (const float*)d_in[6];
  const float* qnw  = (const float*)d_in[7];
  const float* knw  = (const float*)d_in[8];
  const float* aw   = (const float*)d_in[9];
  const float* tw   = (const float*)d_in[10];
  const float* ew   = (const float*)d_in[11];

  float* out = (float*)d_out;
  float* nw1 = out + (size_t)KB*KS*KD;
  float* nw2 = nw1 + (size_t)KB*KI*KD;
  float* nln = nw2 + (size_t)KB*KD*KI;
  float* ns1 = nln + (size_t)KB*KD;
  float* ns2 = ns1 + (size_t)KB*KI*KD;
  float* nsl = ns2 + (size_t)KB*KD*KI;

  float* ws = (float*)d_ws;
  size_t o = 0;
  float* kbuf = ws+o; o += 2097152;   // bf16 silu(x wk^T) pre-rms; later gyb
  float* qbuf = ws+o; o += 2097152;   // bf16 silu(x wq^T) pre-rms; later hq16
  float* gl   = ws+o; o += 32768;
  float* part = ws+o; o += 6144;
  float* cmb  = ws+o; o += 32;
  float* csb  = ws+o; o += 32;
  float* Pwb  = ws+o; o += 32;
  float* thetab = ws+o; o += 32;
  __bf16* bb = (__bf16*)(ws + o);
  size_t p = 0;
  __bf16* xb   = bb+p; p += 2097152;  // reused as gyT
  __bf16* wkb  = bb+p; p += 1048576;  // wkb+wvb reused as kT
  __bf16* wvb  = bb+p; p += 1048576;
  __bf16* wqb  = bb+p; p += 1048576;
  __bf16* w1b  = bb+p; p += 2097152;  // stays live (waccall Winit)
  __bf16* w2b  = bb+p; p += 2097152;  // stays live (waccall Winit)
  __bf16* w2tb = bb+p; p += 2097152;
  __bf16* kb16 = bb+p; p += 2097152;
  __bf16* qb16 = bb+p; p += 2097152;
  __bf16* vb16 = bb+p; p += 2097152;
  __bf16* hb16 = bb+p; p += 4194304;
  __bf16* db16 = bb+p; p += 4194304;  // dsilu(a)
  __bf16* hT   = bb+p; p += 4194304;
  __bf16* gaT  = bb+p; p += 4194304;
  __bf16* nw1b = bb+p; p += 4194304;
  __bf16* nw2b = bb+p; p += 4194304;
  __bf16* y16  = bb+p; p += 4194304;  // y halves; later yq halves
  __bf16* gyT = xb;
  __bf16* kT  = wkb;
  __bf16* kpre16 = (__bf16*)kbuf;     // bf16 pre-rms k
  __bf16* qpre16 = (__bf16*)qbuf;     // bf16 pre-rms q
  __bf16* gyb = (__bf16*)kbuf;        // kpre16 dead after rmsfuse
  __bf16* hq16= (__bf16*)qbuf;        // qpre16 dead after rmsfuse

  dim3 blk(256);

  // 1. prep: convert + gate partials + w2^T + zero gl
  prep_kernel<<<9760, blk, 0, stream>>>(x, wk, wv, wq, w1, w2, aw, tw, ew,
      xb, wkb, wvb, wqb, w1b, w2b, w2tb, part, gl);
  // 2. projections (all-bf16): z0 k->kpre16, z1 v->vb16, z2 q->qpre16
  mgemm2<5,1,0><<<dim3(16,16,3), blk, 0, stream>>>(xb, wkb, wvb, wqb,
      nullptr, nullptr, kpre16, vb16, nullptr, qpre16, 0, 2048, 1024, 1024, 1024, 0);
  // 3. rms k,q -> bf16 (+ scan coefficients at y==2)
  rmsfuse_kernel<<<dim3(512,3), blk, 0, stream>>>(kpre16, knw, kb16, qpre16, qnw, qb16,
      part, cmb, csb, Pwb, thetab);
  // 4. a = k w1^T: h=silu, d=dsilu, hT via epilogue transpose; + kT blocks
  gemm_a_kernel<<<1024, blk, 0, stream>>>(kb16, w1b, hb16, db16, hT, kT);
  // 5. y = h w2^T (split-K 2, bf16 halves)
  mgemm2<6,2,0><<<dim3(16,16,2), blk, 0, stream>>>(hb16, w2b, nullptr, nullptr,
      nullptr, nullptr, y16, nullptr, nullptr, nullptr, 0, 2048, 1024, 2048, 2048, 0);
  // 6. backward through rms+MSE (gy bf16, gl atomics)
  rms_grad_kernel<<<512, blk, 0, stream>>>(y16, kb16, vb16, lnw, thetab, gyb, gl);
  // 7. gaT = ((gy w2tb^T)*dsilu)^T via epilogue transpose; + gyT blocks
  gemm_ga_kernel<<<1024, blk, 0, stream>>>(gyb, w2tb, db16, gaT, gyT);
  // 8. wacc1 + wacc2 + glcomb, 64x64 tiles, 2056 blocks (2x occupancy)
  waccall_kernel<<<2056, blk, 0, stream>>>(gaT, kT, w1b, gyT, hT, w2b, gl, lnw,
      cmb, csb, Pwb, nw1, nw1b, ns1, nw2, nw2b, ns2, nln, nsl);
  // 9. hq = silu(q nw1^T) bf16
  mgemm2<4,0,0><<<dim3(32,16,1), blk, 0, stream>>>(qb16, nw1b, nullptr, nullptr,
      nullptr, nullptr, hq16, nullptr, nullptr, nullptr, 0, 2048, 2048, 1024, 1024, (long)KI*KD);
  // 10. yq = hq nw2^T (split-K 2, bf16 halves)
  mgemm2<6,2,0><<<dim3(16,16,2), blk, 0, stream>>>(hq16, nw2b, nullptr, nullptr,
      nullptr, nullptr, y16, nullptr, nullptr, nullptr, 0, 2048, 1024, 2048, 2048, (long)KD*KI);
  // 11. out = q + rms(yq)*nln
  final_out_kernel<<<512, blk, 0, stream>>>(qb16, y16, nln, out);
}

// Round 15
// 193.476 us; speedup vs baseline: 1.0137x; 1.0137x over previous
//
#include <hip/hip_runtime.h>

#define KD 1024   // D
#define KI 2048   // I
#define KB 2      // B
#define KS 1024   // S
#define KC 64     // C
#define KN 16     // N chunks
#define KEPS 1e-6f

typedef __bf16 bf16x8 __attribute__((ext_vector_type(8)));
typedef __bf16 bf16x4 __attribute__((ext_vector_type(4)));
typedef float f32x4 __attribute__((ext_vector_type(4)));

__device__ __forceinline__ float sigf(float x){ return 1.0f/(1.0f+__expf(-x)); }
__device__ __forceinline__ float siluf(float x){ return x*sigf(x); }
__device__ __forceinline__ float dsiluf(float x){ float s=sigf(x); return s*(1.0f+x*(1.0f-s)); }

// width-16 global->LDS DMA; LDS dest is wave-uniform base + lane*16
__device__ __forceinline__ void gld16(const __bf16* g, __bf16* l) {
  __builtin_amdgcn_global_load_lds(
    (const __attribute__((address_space(1))) unsigned int*)g,
    (__attribute__((address_space(3))) unsigned int*)l, 16, 0, 0);
}

#define WAIT_VM6()  asm volatile("s_waitcnt vmcnt(6)" ::: "memory")
#define WAIT_VM0()  asm volatile("s_waitcnt vmcnt(0)" ::: "memory")
#define WAIT_LGKM() asm volatile("s_waitcnt lgkmcnt(0)" ::: "memory")
#define BAR()       __builtin_amdgcn_s_barrier()

// ---------------- transpose body, caller LDS (needs >= 64*65 floats) -------
__device__ __forceinline__ void tconv_bodyP(float* T, const __bf16* in, __bf16* out,
                                            int R, int Cc, int bx, int by)
{
  const int r0 = by*64, c0 = bx*64;
  const int tx = threadIdx.x & 15, ty = threadIdx.x >> 4;
  #pragma unroll
  for (int i=0;i<4;i++){
    const int r = r0 + ty + i*16;
    const bf16x4 v = *(const bf16x4*)(in + (size_t)r*Cc + c0 + tx*4);
    T[(ty+i*16)*65 + tx*4+0]=(float)v[0]; T[(ty+i*16)*65 + tx*4+1]=(float)v[1];
    T[(ty+i*16)*65 + tx*4+2]=(float)v[2]; T[(ty+i*16)*65 + tx*4+3]=(float)v[3];
  }
  __syncthreads();
  #pragma unroll
  for (int i=0;i<4;i++){
    bf16x4 o = { (__bf16)T[(tx*4+0)*65 + ty+i*16], (__bf16)T[(tx*4+1)*65 + ty+i*16],
                 (__bf16)T[(tx*4+2)*65 + ty+i*16], (__bf16)T[(tx*4+3)*65 + ty+i*16] };
    *(bf16x4*)(out + (size_t)(c0+ty+i*16)*R + r0 + tx*4) = o;
  }
}

// fp32-source transpose with own LDS (prep only)
__device__ __forceinline__ void tconv_bodyF(const float* in, __bf16* out,
                                            int R, int Cc, int bx, int by)
{
  __shared__ float T[64][65];
  const int r0 = by*64, c0 = bx*64;
  const int tx = threadIdx.x & 15, ty = threadIdx.x >> 4;
  #pragma unroll
  for (int i=0;i<4;i++){
    const int r = r0 + ty + i*16;
    const float4 v = *(const float4*)(in + (size_t)r*Cc + c0 + tx*4);
    T[ty+i*16][tx*4+0]=v.x; T[ty+i*16][tx*4+1]=v.y;
    T[ty+i*16][tx*4+2]=v.z; T[ty+i*16][tx*4+3]=v.w;
  }
  __syncthreads();
  #pragma unroll
  for (int i=0;i<4;i++){
    bf16x4 o = { (__bf16)T[tx*4+0][ty+i*16], (__bf16)T[tx*4+1][ty+i*16],
                 (__bf16)T[tx*4+2][ty+i*16], (__bf16)T[tx*4+3][ty+i*16] };
    *(bf16x4*)(out + (size_t)(c0+ty+i*16)*R + r0 + tx*4) = o;
  }
}

// ---------------- prep: convert (x-blocks also gate partials) + w2^T + gl=0
__global__ __launch_bounds__(256) void prep_kernel(
  const float* __restrict__ x, const float* __restrict__ wk, const float* __restrict__ wv,
  const float* __restrict__ wq, const float* __restrict__ w1, const float* __restrict__ w2,
  const float* __restrict__ aw, const float* __restrict__ tw, const float* __restrict__ ew,
  __bf16* __restrict__ xb, __bf16* __restrict__ wkb, __bf16* __restrict__ wvb,
  __bf16* __restrict__ wqb, __bf16* __restrict__ w1b, __bf16* __restrict__ w2b,
  __bf16* __restrict__ w2tb, float* __restrict__ part, float* __restrict__ gl)
{
  const int g = blockIdx.x;
  if (g < 2048) {
    const int i = g*256 + threadIdx.x;          // float4 index into x
    const float4 xv = *(const float4*)(x + (size_t)i*4);
    bf16x4 o = { (__bf16)xv.x, (__bf16)xv.y, (__bf16)xv.z, (__bf16)xv.w };
    *(bf16x4*)(xb + (size_t)i*4) = o;
    const size_t co = (size_t)(i & 16383) * 4;  // chunk-local element offset
    const float4 av = *(const float4*)(aw + co);
    const float4 tv = *(const float4*)(tw + co);
    const float4 ev = *(const float4*)(ew + co);
    float da = xv.x*av.x + xv.y*av.y + xv.z*av.z + xv.w*av.w;
    float dt = xv.x*tv.x + xv.y*tv.y + xv.z*tv.z + xv.w*tv.w;
    float de = xv.x*ev.x + xv.y*ev.y + xv.z*ev.z + xv.w*ev.w;
    __shared__ float sA[256], sT[256], sE[256];
    sA[threadIdx.x]=da; sT[threadIdx.x]=dt; sE[threadIdx.x]=de;
    __syncthreads();
    for (int s=128;s>0;s>>=1){
      if ((int)threadIdx.x < s){
        sA[threadIdx.x]+=sA[threadIdx.x+s];
        sT[threadIdx.x]+=sT[threadIdx.x+s];
        sE[threadIdx.x]+=sE[threadIdx.x+s];
      }
      __syncthreads();
    }
    if (threadIdx.x==0){
      part[g] = sA[0]; part[2048+g] = sT[0]; part[4096+g] = sE[0];
    }
  } else if (g < 9216) {
    const long t = (long)g*256 + threadIdx.x;   // float4 index
    const float* s; __bf16* d; long i;
    if (t < 786432)       { s=wk; d=wkb; i=t-524288; }
    else if (t < 1048576) { s=wv; d=wvb; i=t-786432; }
    else if (t < 1310720) { s=wq; d=wqb; i=t-1048576; }
    else if (t < 1835008) { s=w1; d=w1b; i=t-1310720; }
    else                  { s=w2; d=w2b; i=t-1835008; }
    const float4 v = *(const float4*)(s + i*4);
    bf16x4 o = { (__bf16)v.x, (__bf16)v.y, (__bf16)v.z, (__bf16)v.w };
    *(bf16x4*)(d + i*4) = o;
  } else if (g < 9728) {
    const int gg = g - 9216;
    tconv_bodyF(w2, w2tb, 1024, 2048, gg & 31, gg >> 5);
  } else {
    const int gg = g - 9728;                    // 32 blocks zero gl
    float4 z = {0.f,0.f,0.f,0.f};
    *(float4*)(gl + (size_t)gg*1024 + threadIdx.x*4) = z;
  }
}

// ---------------- MFMA bf16 GEMM body, counted-vmcnt: C = A*B^T ------------
// BM=128, BN=64, BK=64, K=1024 (16 steps). 4 waves, wave tile 64x32.
// Prefetch loads for t+1 stay IN FLIGHT across the barriers (vmcnt(6), not 0).
// MODE: 0 plain, 1 proj mux (z selects B), 2 k-split (z = K half)
// EPI: 0 F0=acc; 2 Oa=silu & Ob=dsilu (+WT: OT=silu^T);
//      3 (WT) OT=(acc*Aux)^T only; 4 Oa=silu; 6 Oa[z*M*N]=bf16(acc);
//      5 proj mux all-bf16: bz0->Oa, bz1->Ob, bz2->OT (silu)
template<int EPI, int MODE, int WT>
__device__ __forceinline__ void mgemm_body(
    __bf16* As, __bf16* Bs,
    const __bf16* __restrict__ A, const __bf16* __restrict__ B0,
    const __bf16* __restrict__ B1, const __bf16* __restrict__ B2,
    float* __restrict__ F0, float* __restrict__ F1,
    __bf16* __restrict__ Oa, __bf16* __restrict__ Ob, const __bf16* __restrict__ Aux,
    __bf16* __restrict__ OT, int ldt,
    int M, int Nn, int lda, int ldb, long bstr,
    int bx, int by, int bz)
{
  const int n0 = bx * 64;
  const int m0 = by * 128;
  const __bf16* Bp = B0;
  if (MODE==1) { if (bz==1) Bp=B1; else if (bz==2) Bp=B2; }
  float* F0p = F0;
  int koff0 = 0;
  if (MODE==2) { koff0 = bz << 10; }
  Bp += (size_t)(m0 >> 10) * (size_t)bstr;
  const int tid = threadIdx.x, wv = tid >> 6, lane = tid & 63;
  const int wm = (wv >> 1) << 6, wn = (wv & 1) << 5;
  const int fr = lane & 15, fg = lane >> 4;
  const int lr = lane >> 3, lc = lane & 7;
  const __bf16* asrc[4]; __bf16* adst[4];
  const __bf16* bsrc[2]; __bf16* bdst[2];
  #pragma unroll
  for (int i=0;i<4;i++){
    const int rowbase=(wv*4+i)*8, row=rowbase+lr;
    asrc[i] = A + (size_t)(m0+row)*lda + koff0 + ((lc^(row&7))<<3);
    adst[i] = As + rowbase*64;
  }
  #pragma unroll
  for (int i=0;i<2;i++){
    const int rowbase=(wv*2+i)*8, row=rowbase+lr;
    bsrc[i] = Bp + (size_t)(n0+row)*ldb + koff0 + ((lc^(row&7))<<3);
    bdst[i] = Bs + rowbase*64;
  }
  f32x4 acc[4][2] = {};
  #pragma unroll
  for (int i=0;i<4;i++) gld16(asrc[i], adst[i]);
  #pragma unroll
  for (int i=0;i<2;i++) gld16(bsrc[i], bdst[i]);
  WAIT_VM0();
  BAR();
  #pragma unroll 2
  for (int t=0;t<16;++t){
    const int p = t & 1;
    if (t < 15){
      const int ko = (t+1) << 6;
      const int q = p ^ 1;
      #pragma unroll
      for (int i=0;i<4;i++) gld16(asrc[i]+ko, adst[i]+q*8192);
      #pragma unroll
      for (int i=0;i<2;i++) gld16(bsrc[i]+ko, bdst[i]+q*4096);
      WAIT_VM6();            // loads(t) done; loads(t+1) stay in flight
    } else {
      WAIT_VM0();
    }
    BAR();
    #pragma unroll
    for (int ks=0;ks<2;++ks){
      bf16x8 af[4], bfv[2];
      #pragma unroll
      for (int mi=0;mi<4;++mi){
        const int r = wm + mi*16 + fr;
        af[mi] = *(const bf16x8*)(As + p*8192 + r*64 + ((((ks<<2)+fg)^(r&7))<<3));
      }
      #pragma unroll
      for (int ni=0;ni<2;++ni){
        const int r = wn + ni*16 + fr;
        bfv[ni] = *(const bf16x8*)(Bs + p*4096 + r*64 + ((((ks<<2)+fg)^(r&7))<<3));
      }
      #pragma unroll
      for (int mi=0;mi<4;++mi)
        #pragma unroll
        for (int ni=0;ni<2;++ni)
          acc[mi][ni] = __builtin_amdgcn_mfma_f32_16x16x32_bf16(af[mi], bfv[ni], acc[mi][ni], 0,0,0);
    }
    WAIT_LGKM();             // all LDS reads landed in regs before buffer reuse
    BAR();
  }
  __bf16* T = As;   // reuse staging LDS for transpose epilogue
  #pragma unroll
  for (int mi=0;mi<4;++mi){
    #pragma unroll
    for (int ni=0;ni<2;++ni){
      bf16x4 tv;
      #pragma unroll
      for (int j=0;j<4;++j){
        const int m = m0 + wm + mi*16 + fg*4 + j;
        const int n = n0 + wn + ni*16 + fr;
        const size_t idx = (size_t)m * Nn + n;
        const float v = acc[mi][ni][j];
        float tval = 0.f;
        if (EPI==0) F0p[idx] = v;
        else if (EPI==2) { const float sv = siluf(v); Oa[idx]=(__bf16)sv; Ob[idx]=(__bf16)dsiluf(v); tval=sv; }
        else if (EPI==3) tval = v * (float)Aux[idx];
        else if (EPI==4) Oa[idx] = (__bf16)siluf(v);
        else if (EPI==5) {
          const __bf16 sv = (__bf16)siluf(v);
          if (bz==0) Oa[idx] = sv;
          else if (bz==1) Ob[idx] = sv;
          else OT[idx] = sv;
        }
        else if (EPI==6) Oa[(size_t)bz*M*Nn + idx] = (__bf16)v;
        if (WT) tv[j] = (__bf16)tval;
      }
      if (WT){
        const int nl = wn + ni*16 + fr;
        const int ml = wm + mi*16 + fg*4;
        *(bf16x4*)(T + nl*128 + (ml ^ ((nl&7)<<3))) = tv;
      }
    }
  }
  if (WT){
    __syncthreads();
    const int tn = tid >> 2, tc = tid & 3;
    #pragma unroll
    for (int u=0;u<4;++u){
      const int m8 = tc*32 + u*8;
      const bf16x8 v = *(const bf16x8*)(T + tn*128 + (m8 ^ ((tn&7)<<3)));
      *(bf16x8*)(OT + (size_t)(n0+tn)*ldt + m0 + m8) = v;
    }
  }
}

template<int EPI, int MODE, int WT>
__global__ __launch_bounds__(256) void mgemm2(
    const __bf16* __restrict__ A, const __bf16* __restrict__ B0,
    const __bf16* __restrict__ B1, const __bf16* __restrict__ B2,
    float* __restrict__ F0, float* __restrict__ F1,
    __bf16* __restrict__ Oa, __bf16* __restrict__ Ob, const __bf16* __restrict__ Aux,
    __bf16* __restrict__ OT, int ldt,
    int M, int Nn, int lda, int ldb, long bstr)
{
  __shared__ __bf16 As[2*128*64];
  __shared__ __bf16 Bs[2*64*64];
  mgemm_body<EPI,MODE,WT>(As, Bs, A, B0, B1, B2, F0, F1, Oa, Ob, Aux, OT, ldt,
                          M, Nn, lda, ldb, bstr, blockIdx.x, blockIdx.y, blockIdx.z);
}

// ---------------- a-GEMM (h,dsilu,hT) + kT transpose in one launch ---------
__global__ __launch_bounds__(256) void gemm_a_kernel(
    const __bf16* __restrict__ kb16, const __bf16* __restrict__ w1b,
    __bf16* __restrict__ hb16, __bf16* __restrict__ db16, __bf16* __restrict__ hT,
    __bf16* __restrict__ kT)
{
  __shared__ __bf16 As[2*128*64];
  __shared__ __bf16 Bs[2*64*64];
  const int g = blockIdx.x;
  if (g < 512)
    mgemm_body<2,0,1>(As, Bs, kb16, w1b, nullptr, nullptr, nullptr, nullptr,
                      hb16, db16, nullptr, hT, 2048, 2048, 2048, 1024, 1024, 0,
                      g & 31, g >> 5, 0);
  else {
    const int t = g - 512;
    tconv_bodyP((float*)As, kb16, kT, 2048, 1024, t & 15, t >> 4);
  }
}

// ---------------- ga-GEMM (gaT only) + gyT transpose in one launch ---------
__global__ __launch_bounds__(256) void gemm_ga_kernel(
    const __bf16* __restrict__ gyb, const __bf16* __restrict__ w2tb,
    const __bf16* __restrict__ db16, __bf16* __restrict__ gaT,
    __bf16* __restrict__ gyT)
{
  __shared__ __bf16 As[2*128*64];
  __shared__ __bf16 Bs[2*64*64];
  const int g = blockIdx.x;
  if (g < 512)
    mgemm_body<3,0,1>(As, Bs, gyb, w2tb, nullptr, nullptr, nullptr, nullptr,
                      nullptr, nullptr, db16, gaT, 2048, 2048, 2048, 1024, 1024, 0,
                      g & 31, g >> 5, 0);
  else {
    const int t = g - 512;
    tconv_bodyP((float*)As, gyb, gyT, 2048, 1024, t & 15, t >> 4);
  }
}

// ---------------- dual scan-weighted GEMM body (counted-vmcnt) -------------
__device__ __forceinline__ void wacc_body(
    __bf16* As, __bf16* Bs,
    const __bf16* __restrict__ A, const __bf16* __restrict__ B,
    const __bf16* __restrict__ Winit,
    const float* __restrict__ cm, const float* __restrict__ cs,
    const float* __restrict__ Pw,
    float* __restrict__ outM, __bf16* __restrict__ outMb, float* __restrict__ outS,
    int M, int Nn, int lda, int ldb, int n0, int m0, int bz)
{
  const int koff0 = bz << 10;
  const int tid = threadIdx.x, wv = tid >> 6, lane = tid & 63;
  const int wm = (wv >> 1) << 6, wn = (wv & 1) << 5;
  const int fr = lane & 15, fg = lane >> 4;
  const int lr = lane >> 3, lc = lane & 7;
  // preload scan coefficients BEFORE any staging so no VMEM op pollutes the
  // in-loop vmcnt count
  float cmr[KN], csr[KN];
  #pragma unroll
  for (int n=0;n<KN;n++){ cmr[n]=cm[bz*KN+n]; csr[n]=cs[bz*KN+n]; }
  const __bf16* asrc[4]; __bf16* adst[4];
  const __bf16* bsrc[2]; __bf16* bdst[2];
  #pragma unroll
  for (int i=0;i<4;i++){
    const int rowbase=(wv*4+i)*8, row=rowbase+lr;
    asrc[i] = A + (size_t)(m0+row)*lda + koff0 + ((lc^(row&7))<<3);
    adst[i] = As + rowbase*64;
  }
  #pragma unroll
  for (int i=0;i<2;i++){
    const int rowbase=(wv*2+i)*8, row=rowbase+lr;
    bsrc[i] = B + (size_t)(n0+row)*ldb + koff0 + ((lc^(row&7))<<3);
    bdst[i] = Bs + rowbase*64;
  }
  f32x4 accM[4][2] = {}, accS[4][2] = {};
  asm volatile("s_waitcnt vmcnt(0) lgkmcnt(0)" ::: "memory");  // fence preloads
  #pragma unroll
  for (int i=0;i<4;i++) gld16(asrc[i], adst[i]);
  #pragma unroll
  for (int i=0;i<2;i++) gld16(bsrc[i], bdst[i]);
  WAIT_VM0();
  BAR();
  #pragma unroll 2
  for (int t=0;t<16;++t){
    const int p = t & 1;
    const float cmc = cmr[t], csc = csr[t];
    if (t < 15){
      const int ko = (t+1) << 6;
      const int q = p ^ 1;
      #pragma unroll
      for (int i=0;i<4;i++) gld16(asrc[i]+ko, adst[i]+q*8192);
      #pragma unroll
      for (int i=0;i<2;i++) gld16(bsrc[i]+ko, bdst[i]+q*4096);
      WAIT_VM6();
    } else {
      WAIT_VM0();
    }
    BAR();
    bf16x8 a0[4], a1[4], b0[2], b1[2];
    #pragma unroll
    for (int mi=0;mi<4;++mi){
      const int r = wm + mi*16 + fr;
      a0[mi] = *(const bf16x8*)(As + p*8192 + r*64 + (((0+fg)^(r&7))<<3));
      a1[mi] = *(const bf16x8*)(As + p*8192 + r*64 + (((4+fg)^(r&7))<<3));
    }
    #pragma unroll
    for (int ni=0;ni<2;++ni){
      const int r = wn + ni*16 + fr;
      b0[ni] = *(const bf16x8*)(Bs + p*4096 + r*64 + (((0+fg)^(r&7))<<3));
      b1[ni] = *(const bf16x8*)(Bs + p*4096 + r*64 + (((4+fg)^(r&7))<<3));
    }
    #pragma unroll
    for (int mi=0;mi<4;++mi){
      #pragma unroll
      for (int ni=0;ni<2;++ni){
        const f32x4 zf = {0.f,0.f,0.f,0.f};
        f32x4 P = __builtin_amdgcn_mfma_f32_16x16x32_bf16(a0[mi], b0[ni], zf, 0,0,0);
        P = __builtin_amdgcn_mfma_f32_16x16x32_bf16(a1[mi], b1[ni], P, 0,0,0);
        accM[mi][ni] += P * cmc;
        accS[mi][ni] += P * csc;
      }
    }
    WAIT_LGKM();
    BAR();
  }
  const float pw = Pw[bz];
  float* Tf = (float*)As;   // 32 KB = 128x64 fp32 tile
  const int orow = tid >> 4, oc4 = (tid & 15) << 2;
  // ---- M output: stage, then coalesced 256B-row writes (+bf16 copy) ----
  #pragma unroll
  for (int mi=0;mi<4;++mi){
    #pragma unroll
    for (int ni=0;ni<2;++ni){
      #pragma unroll
      for (int j=0;j<4;++j){
        const int ml = wm + mi*16 + fg*4 + j;
        const int nl = wn + ni*16 + fr;
        const size_t widx = (size_t)(m0+ml)*Nn + (n0+nl);
        Tf[ml*64 + nl] = pw * (float)Winit[widx] + accM[mi][ni][j];
      }
    }
  }
  __syncthreads();
  #pragma unroll
  for (int ps=0; ps<8; ++ps){
    const int r = orow + ps*16;
    const float4 v = *(const float4*)&Tf[r*64 + oc4];
    const size_t oidx = (size_t)bz*M*Nn + (size_t)(m0+r)*Nn + n0 + oc4;
    *(float4*)&outM[oidx] = v;
    bf16x4 vb = { (__bf16)v.x, (__bf16)v.y, (__bf16)v.z, (__bf16)v.w };
    *(bf16x4*)&outMb[oidx] = vb;
  }
  __syncthreads();
  // ---- S output ----
  #pragma unroll
  for (int mi=0;mi<4;++mi){
    #pragma unroll
    for (int ni=0;ni<2;++ni){
      #pragma unroll
      for (int j=0;j<4;++j){
        const int ml = wm + mi*16 + fg*4 + j;
        const int nl = wn + ni*16 + fr;
        Tf[ml*64 + nl] = accS[mi][ni][j];
      }
    }
  }
  __syncthreads();
  #pragma unroll
  for (int ps=0; ps<8; ++ps){
    const int r = orow + ps*16;
    const float4 v = *(const float4*)&Tf[r*64 + oc4];
    const size_t oidx = (size_t)bz*M*Nn + (size_t)(m0+r)*Nn + n0 + oc4;
    *(float4*)&outS[oidx] = v;
  }
}

// ---------------- merged wacc1 + wacc2 + glcomb ----------------------------
// Section-local XCD swizzle: each 512-block section remapped so each XCD gets
// a contiguous 64-block run (panel reuse in its private L2) while the
// wacc1/wacc2/glcomb interleave across XCDs is preserved.
__global__ __launch_bounds__(256) void waccall_kernel(
    const __bf16* __restrict__ gaT, const __bf16* __restrict__ kT, const __bf16* __restrict__ w1b,
    const __bf16* __restrict__ gyT, const __bf16* __restrict__ hT, const __bf16* __restrict__ w2b,
    const float* __restrict__ gl, const float* __restrict__ lnw,
    const float* __restrict__ cm, const float* __restrict__ cs, const float* __restrict__ Pw,
    float* __restrict__ nw1, __bf16* __restrict__ nw1b, float* __restrict__ ns1,
    float* __restrict__ nw2, __bf16* __restrict__ nw2b, float* __restrict__ ns2,
    float* __restrict__ nln, float* __restrict__ nsl)
{
  __shared__ __bf16 As[2*128*64];
  __shared__ __bf16 Bs[2*64*64];
  int g = blockIdx.x;
  if (g < 512) g = ((g & 7) << 6) | (g >> 3);                       // bijective on [0,512)
  else if (g < 1024) { int t = g - 512; g = 512 + (((t & 7) << 6) | (t >> 3)); }
  if (g < 512){
    const int bz = g >> 8, rem = g & 255;
    wacc_body(As, Bs, gaT, kT, w1b, cm, cs, Pw, nw1, nw1b, ns1,
              2048, 1024, 2048, 2048, (rem & 15)*64, (rem >> 4)*128, bz);
  } else if (g < 1024){
    const int t = g - 512;
    const int bz = t >> 8, rem = t & 255;
    wacc_body(As, Bs, gyT, hT, w2b, cm, cs, Pw, nw2, nw2b, ns2,
              1024, 2048, 2048, 2048, (rem & 31)*64, (rem >> 5)*128, bz);
  } else {
    const int idx = (g - 1024)*256 + threadIdx.x;
    const int b = idx >> 10, d = idx & (KD-1);
    float am=0.f, as=0.f;
    for (int n=0;n<KN;n++){
      const float gv = gl[(size_t)(b*KN+n)*KD + d];
      am += cm[b*KN+n]*gv; as += cs[b*KN+n]*gv;
    }
    nln[idx] = Pw[b]*lnw[d] + am;
    nsl[idx] = as;
  }
}

// ---------------- rmsnorm for k,q from bf16 (+ scan coef at y==2) ----------
__global__ __launch_bounds__(256) void rmsfuse_kernel(
    const __bf16* __restrict__ kv, const float* __restrict__ kw, __bf16* __restrict__ k16,
    const __bf16* __restrict__ qv, const float* __restrict__ qw, __bf16* __restrict__ q16,
    const float* __restrict__ part, float* __restrict__ cm, float* __restrict__ cs,
    float* __restrict__ Pw, float* __restrict__ theta)
{
  if (blockIdx.y == 2){
    if (blockIdx.x != 0) return;
    __shared__ float P[32][8][3];
    const int bn = threadIdx.x >> 3, sg = threadIdx.x & 7;
    float s0=0.f, s1=0.f, s2=0.f;
    #pragma unroll
    for (int u=0;u<8;u++){
      const int seg = bn*64 + sg*8 + u;
      s0 += part[seg]; s1 += part[2048+seg]; s2 += part[4096+seg];
    }
    P[bn][sg][0]=s0; P[bn][sg][1]=s1; P[bn][sg][2]=s2;
    __syncthreads();
    if ((int)threadIdx.x < KB){
      const int b = threadIdx.x;
      float al[KN], et[KN];
      for (int n=0;n<KN;n++){
        const int c = b*KN+n;
        float sa=0.f, st=0.f, se=0.f;
        #pragma unroll
        for (int k=0;k<8;k++){ sa+=P[c][k][0]; st+=P[c][k][1]; se+=P[c][k][2]; }
        al[n]=sigf(sa); theta[c]=sigf(st)*0.01f; et[n]=sigf(se);
      }
      float prodE = 1.f;
      for (int j=KN-1;j>=0;j--){ cs[b*KN+j] = -prodE; prodE *= et[j]; }
      float Ac[KN]; Ac[KN-1]=1.f;
      for (int t=KN-2;t>=0;t--) Ac[t] = Ac[t+1]*(1.f-al[t+1]);
      for (int j=0;j<KN;j++){
        float inner=0.f, E=1.f;
        for (int t=j;t<KN;t++){ inner += Ac[t]*E; if (t+1<KN) E *= et[t+1]; }
        cm[b*KN+j] = -inner;
      }
      float pw=1.f;
      for (int n=0;n<KN;n++) pw *= (1.f-al[n]);
      Pw[b]=pw;
    }
    return;
  }
  const __bf16* v; const float* w; __bf16* o16;
  if (blockIdx.y == 0){ v=kv; w=kw; o16=k16; } else { v=qv; w=qw; o16=q16; }
  const int row = blockIdx.x * 4 + (threadIdx.x >> 6);
  const int lane = threadIdx.x & 63;
  const __bf16* pr = v + (size_t)row * KD + lane*16;   // 16 contiguous per lane
  const bf16x8 a0 = *(const bf16x8*)pr;
  const bf16x8 a1 = *(const bf16x8*)(pr + 8);
  float vals[16]; float ss = 0.f;
  #pragma unroll
  for (int j=0;j<8;j++){ vals[j]=(float)a0[j]; vals[8+j]=(float)a1[j]; }
  #pragma unroll
  for (int j=0;j<16;j++) ss += vals[j]*vals[j];
  #pragma unroll
  for (int o=32;o>0;o>>=1) ss += __shfl_xor(ss, o, 64);
  const float inv = rsqrtf(ss * (1.0f/KD) + KEPS);
  const float* wp = w + lane*16;
  const float4 w0 = *(const float4*)(wp),   w1 = *(const float4*)(wp+4);
  const float4 w2 = *(const float4*)(wp+8), w3 = *(const float4*)(wp+12);
  const float wa[16] = { w0.x,w0.y,w0.z,w0.w, w1.x,w1.y,w1.z,w1.w,
                         w2.x,w2.y,w2.z,w2.w, w3.x,w3.y,w3.z,w3.w };
  bf16x8 o0, o1;
  #pragma unroll
  for (int j=0;j<8;j++){
    o0[j] = (__bf16)(vals[j]*inv*wa[j]);
    o1[j] = (__bf16)(vals[8+j]*inv*wa[8+j]);
  }
  __bf16* op = o16 + (size_t)row * KD + lane*16;
  *(bf16x8*)op = o0;
  *(bf16x8*)(op + 8) = o1;
}

// ---------------- per-row backward (y = bf16 halves), gl via atomics -------
__global__ __launch_bounds__(256) void rms_grad_kernel(
    const __bf16* __restrict__ y16,
    const __bf16* __restrict__ k16, const __bf16* __restrict__ v16,
    const float* __restrict__ lnw, const float* __restrict__ theta,
    __bf16* __restrict__ gy, float* __restrict__ gl)
{
  const int wv = threadIdx.x >> 6;
  const int row = blockIdx.x * 4 + wv;
  const int lane = threadIdx.x & 63;
  const int chunk = blockIdx.x >> 4;
  const float th2 = theta[chunk] * (2.0f / KD);
  const __bf16* yr0 = y16 + (size_t)row * KD;
  const __bf16* yr1 = y16 + 2097152 + (size_t)row * KD;
  const __bf16* kr = k16 + (size_t)row * KD;
  const __bf16* vr = v16 + (size_t)row * KD;
  float yv[16]; float ss = 0.f;
  #pragma unroll
  for (int l=0;l<16;l++){
    const int d = lane + (l<<6);
    yv[l] = (float)yr0[d] + (float)yr1[d]; ss += yv[l]*yv[l];
  }
  #pragma unroll
  for (int o=32;o>0;o>>=1) ss += __shfl_xor(ss, o, 64);
  const float inv = rsqrtf(ss * (1.0f/KD) + KEPS);
  float gzv[16]; float sdot = 0.f;
  #pragma unroll
  for (int l=0;l<16;l++){
    const int d = lane + (l<<6);
    const float gz = th2 * ((float)kr[d] + yv[l]*inv*lnw[d] - (float)vr[d]);
    gzv[l] = gz;
    sdot += gz * lnw[d] * yv[l];
  }
  #pragma unroll
  for (int o=32;o>0;o>>=1) sdot += __shfl_xor(sdot, o, 64);
  const float c3 = inv*inv*inv * (1.0f/KD) * sdot;
  __bf16* gyr = gy + (size_t)row * KD;
  __shared__ float L[4][KD];
  #pragma unroll
  for (int l=0;l<16;l++){
    const int d = lane + (l<<6);
    gyr[d] = (__bf16)(inv * lnw[d] * gzv[l] - c3 * yv[l]);
    L[wv][d] = gzv[l] * yv[l] * inv;
  }
  __syncthreads();
  if (wv == 0){
    float* glc = gl + (size_t)chunk * KD;
    #pragma unroll
    for (int l=0;l<16;l++){
      const int d = lane + (l<<6);
      atomicAdd(&glc[d], L[0][d]+L[1][d]+L[2][d]+L[3][d]);
    }
  }
}

// ---------------- final out (yq = bf16 halves, q from bf16) ----------------
__global__ __launch_bounds__(256) void final_out_kernel(
    const __bf16* __restrict__ q16, const __bf16* __restrict__ yq16,
    const float* __restrict__ nln, float* __restrict__ out)
{
  const int row = blockIdx.x * 4 + (threadIdx.x >> 6);
  const int lane = threadIdx.x & 63;
  const int b = row >> 10;
  float yv[16]; float ss = 0.f;
  #pragma unroll
  for (int l=0;l<16;l++){
    const int d = lane + (l<<6);
    yv[l] = (float)yq16[(size_t)row*KD + d] + (float)yq16[2097152 + (size_t)row*KD + d];
    ss += yv[l]*yv[l];
  }
  #pragma unroll
  for (int o=32;o>0;o>>=1) ss += __shfl_xor(ss, o, 64);
  const float inv = rsqrtf(ss * (1.0f/KD) + KEPS);
  #pragma unroll
  for (int l=0;l<16;l++){
    const int d = lane + (l<<6);
    out[(size_t)row*KD + d] = (float)q16[(size_t)row*KD + d] + yv[l]*inv*nln[b*KD + d];
  }
}

extern "C" void kernel_launch(void* const* d_in, const int* in_sizes, int n_in,
                              void* d_out, int out_size, void* d_ws, size_t ws_size,
                              hipStream_t stream)
{
  const float* x    = (const float*)d_in[0];
  const float* w1   = (const float*)d_in[1];
  const float* w2   = (const float*)d_in[2];
  const float* lnw  = (const float*)d_in[3];
  const float* wq   = (const float*)d_in[4];
  const float* wk   = (const float*)d_in[5];
  const float* wv   = (const float*)d_in[6];
  const float* qnw  = (const float*)d_in[7];
  const float* knw  = (const float*)d_in[8];
  const float* aw   = (const float*)d_in[9];
  const float* tw   = (const float*)d_in[10];
  const float* ew   = (const float*)d_in[11];

  float* out = (float*)d_out;
  float* nw1 = out + (size_t)KB*KS*KD;
  float* nw2 = nw1 + (size_t)KB*KI*KD;
  float* nln = nw2 + (size_t)KB*KD*KI;
  float* ns1 = nln + (size_t)KB*KD;
  float* ns2 = ns1 + (size_t)KB*KI*KD;
  float* nsl = ns2 + (size_t)KB*KD*KI;

  float* ws = (float*)d_ws;
  size_t o = 0;
  float* kbuf = ws+o; o += 2097152;   // bf16 silu(x wk^T) pre-rms; later gyb
  float* qbuf = ws+o; o += 2097152;   // bf16 silu(x wq^T) pre-rms; later hq16
  float* gl   = ws+o; o += 32768;
  float* part = ws+o; o += 6144;
  float* cmb  = ws+o; o += 32;
  float* csb  = ws+o; o += 32;
  float* Pwb  = ws+o; o += 32;
  float* thetab = ws+o; o += 32;
  __bf16* bb = (__bf16*)(ws + o);
  size_t p = 0;
  __bf16* xb   = bb+p; p += 2097152;  // reused as gyT
  __bf16* wkb  = bb+p; p += 1048576;  // wkb+wvb reused as kT
  __bf16* wvb  = bb+p; p += 1048576;
  __bf16* wqb  = bb+p; p += 1048576;
  __bf16* w1b  = bb+p; p += 2097152;  // stays live (waccall Winit)
  __bf16* w2b  = bb+p; p += 2097152;  // stays live (waccall Winit)
  __bf16* w2tb = bb+p; p += 2097152;
  __bf16* kb16 = bb+p; p += 2097152;
  __bf16* qb16 = bb+p; p += 2097152;
  __bf16* vb16 = bb+p; p += 2097152;
  __bf16* hb16 = bb+p; p += 4194304;
  __bf16* db16 = bb+p; p += 4194304;  // dsilu(a)
  __bf16* hT   = bb+p; p += 4194304;
  __bf16* gaT  = bb+p; p += 4194304;
  __bf16* nw1b = bb+p; p += 4194304;
  __bf16* nw2b = bb+p; p += 4194304;
  __bf16* y16  = bb+p; p += 4194304;  // y halves; later yq halves
  __bf16* gyT = xb;
  __bf16* kT  = wkb;
  __bf16* kpre16 = (__bf16*)kbuf;     // bf16 pre-rms k
  __bf16* qpre16 = (__bf16*)qbuf;     // bf16 pre-rms q
  __bf16* gyb = (__bf16*)kbuf;        // kpre16 dead after rmsfuse
  __bf16* hq16= (__bf16*)qbuf;        // qpre16 dead after rmsfuse

  dim3 blk(256);

  // 1. prep: convert + gate partials + w2^T + zero gl
  prep_kernel<<<9760, blk, 0, stream>>>(x, wk, wv, wq, w1, w2, aw, tw, ew,
      xb, wkb, wvb, wqb, w1b, w2b, w2tb, part, gl);
  // 2. projections (all-bf16): z0 k->kpre16, z1 v->vb16, z2 q->qpre16
  mgemm2<5,1,0><<<dim3(16,16,3), blk, 0, stream>>>(xb, wkb, wvb, wqb,
      nullptr, nullptr, kpre16, vb16, nullptr, qpre16, 0, 2048, 1024, 1024, 1024, 0);
  // 3. rms k,q -> bf16 (+ scan coefficients at y==2)
  rmsfuse_kernel<<<dim3(512,3), blk, 0, stream>>>(kpre16, knw, kb16, qpre16, qnw, qb16,
      part, cmb, csb, Pwb, thetab);
  // 4. a = k w1^T: h=silu, d=dsilu, hT via epilogue transpose; + kT blocks
  gemm_a_kernel<<<1024, blk, 0, stream>>>(kb16, w1b, hb16, db16, hT, kT);
  // 5. y = h w2^T (split-K 2, bf16 halves)
  mgemm2<6,2,0><<<dim3(16,16,2), blk, 0, stream>>>(hb16, w2b, nullptr, nullptr,
      nullptr, nullptr, y16, nullptr, nullptr, nullptr, 0, 2048, 1024, 2048, 2048, 0);
  // 6. backward through rms+MSE (gy bf16, gl atomics)
  rms_grad_kernel<<<512, blk, 0, stream>>>(y16, kb16, vb16, lnw, thetab, gyb, gl);
  // 7. gaT = ((gy w2tb^T)*dsilu)^T via epilogue transpose; + gyT blocks
  gemm_ga_kernel<<<1024, blk, 0, stream>>>(gyb, w2tb, db16, gaT, gyT);
  // 8. wacc1 + wacc2 + glcomb in one launch (section-local XCD swizzle)
  waccall_kernel<<<1032, blk, 0, stream>>>(gaT, kT, w1b, gyT, hT, w2b, gl, lnw,
      cmb, csb, Pwb, nw1, nw1b, ns1, nw2, nw2b, ns2, nln, nsl);
  // 9. hq = silu(q nw1^T) bf16
  mgemm2<4,0,0><<<dim3(32,16,1), blk, 0, stream>>>(qb16, nw1b, nullptr, nullptr,
      nullptr, nullptr, hq16, nullptr, nullptr, nullptr, 0, 2048, 2048, 1024, 1024, (long)KI*KD);
  // 10. yq = hq nw2^T (split-K 2, bf16 halves)
  mgemm2<6,2,0><<<dim3(16,16,2), blk, 0, stream>>>(hq16, nw2b, nullptr, nullptr,
      nullptr, nullptr, y16, nullptr, nullptr, nullptr, 0, 2048, 1024, 2048, 2048, (long)KD*KI);
  // 11. out = q + rms(yq)*nln
  final_out_kernel<<<512, blk, 0, stream>>>(qb16, y16, nln, out);
}